// Round 19
// baseline (72.773 us; speedup 1.0000x reference)
//
#include <hip/hip_runtime.h>
#include <math.h>

typedef unsigned short ushort_t;
typedef unsigned int uint_t;
typedef __attribute__((ext_vector_type(8))) short short8v;   // 8 bf16 (4 VGPR)
typedef __attribute__((ext_vector_type(4))) float f32x4;

#define NEG_MAX (-3.402823466e+38f)

// -------- ws layout (float offsets) --------
#define OFF_KH    0
#define OFF_VP    4194304
#define OFF_GATES 6291456
#define OFF_XHI   8388608
#define OFF_ATTHI OFF_XHI                  // aliases xhi (dead after proj)
#define OFF_BTHI  12582912
#define OFF_BTLO  12713984
#define OFF_QTH   12845056
#define OFF_BIASP 12976128
#define OFF_MASK  13500416
#define OFF_PSUM  13504512                 // [4][256][256] f32 partial sums

// ---------------------------------------------------------------------------
__device__ __forceinline__ ushort_t f2bf(float x) {
    uint_t u = __float_as_uint(x);
    u = (u + 0x7fffu + ((u >> 16) & 1u)) >> 16;   // RNE
    return (ushort_t)u;
}
__device__ __forceinline__ float bf2f(ushort_t u) {
    return __uint_as_float(((uint_t)u) << 16);
}
__device__ __forceinline__ void gl2lds16(const void* g, void* l) {
    typedef const __attribute__((address_space(1))) uint32_t* gptr_t;
    typedef __attribute__((address_space(3))) uint32_t* lptr_t;
    __builtin_amdgcn_global_load_lds((gptr_t)(uintptr_t)g,
                                     (lptr_t)(uintptr_t)l, 16, 0, 0);
}

// ---------------------------------------------------------------------------
// Fused prep kernel. Block ranges:
// [0,1) mask bitpack | [1,1025) wsplit | [1025,1537) bias_prepack
// [1537,2561) x->bf16 split + batch-mean partial sums (1024 blocks, 4/CU)
__global__ __launch_bounds__(256) void prep_kernel(
    const float* __restrict__ x, const unsigned char* __restrict__ mraw,
    const float* __restrict__ bias, const float* __restrict__ Wkv,
    const float* __restrict__ Wg, const float* __restrict__ Wo,
    ushort_t* __restrict__ xhi,
    uint_t* __restrict__ maskb,
    ushort_t* __restrict__ bthi, ushort_t* __restrict__ btlo,
    float* __restrict__ biasP, float* __restrict__ ps) {
    __shared__ int cnt[256];
    const int bid = blockIdx.x, t = threadIdx.x;
    if (bid < 1) {                            // ---- mask bitpack ----
        int c = 0;
        for (int i = t; i < 4096; i += 256)
            if ((i & 3) != 0 && mraw[i] != 0) c++;
        cnt[t] = c;
        __syncthreads();
        for (int s = 128; s > 0; s >>= 1) {
            if (t < s) cnt[t] += cnt[t + s];
            __syncthreads();
        }
        int isBool = cnt[0] > 16;
        const int* mi32 = (const int*)mraw;
#pragma unroll
        for (int wq = 0; wq < 2; wq++) {
            int widx = t * 2 + wq;            // 0..511 = b*8 + (j>>5)
            int j0 = widx * 32;
            uint_t wordv = 0;
            if (isBool) {
                for (int k = 0; k < 32; k++)
                    wordv |= (mraw[j0 + k] ? 1u : 0u) << k;
            } else {
                for (int k = 0; k < 32; k++)
                    wordv |= (mi32[j0 + k] ? 1u : 0u) << k;
            }
            maskb[widx] = wordv;
        }
    } else if (bid < 1025) {                  // ---- wsplit ----
        int idx = (bid - 1) * 256 + t;
        int n = idx >> 8, k = idx & 255;
        float v;
        if (n < 512)      v = Wkv[(size_t)k * 512 + n];
        else if (n < 768) v = Wg[(size_t)k * 256 + (n - 512)];
        else              v = Wo[(size_t)k * 256 + (n - 768)];
        ushort_t h = f2bf(v);
        bthi[idx] = h;
        btlo[idx] = f2bf(v - bf2f(h));
    } else if (bid < 1537) {                  // ---- bias prepack ----
        int idx = (bid - 1025) * 256 + t;     // 0..131071
        int lane = idx & 63, g2 = idx >> 6;   // g2 0..2047
        int mf = g2 & 3, nf = (g2 >> 2) & 1, jt = (g2 >> 3) & 3;
        int iq = (g2 >> 5) & 7, h = g2 >> 8;
        int lr = lane & 15, lg = lane >> 4;
        float4 v = *(const float4*)(bias +
            (size_t)(h * 256 + iq * 32 + nf * 16 + lr) * 256 +
            jt * 64 + mf * 16 + lg * 4);
        *(float4*)(biasP + (size_t)idx * 4) = v;
    } else {                                  // ---- x split + partial mean ----
        int vb2 = bid - 1537;                 // 0..1023
        int i = vb2 >> 2, qu = vb2 & 3;
        float ssum = 0.f;
#pragma unroll 4
        for (int b8 = qu * 16; b8 < qu * 16 + 16; b8++) {
            size_t idx = (size_t)(b8 * 256 + i) * 256 + t;
            float v = x[idx];
            xhi[idx] = f2bf(v);
            ssum += v;
        }
        ps[((size_t)qu * 256 + i) * 256 + t] = ssum;
    }
}

// ---------------------------------------------------------------------------
// Double-buffered MFMA split-bf16 GEMM, XCD-swizzled over nwg_gemm blocks.
// EPI==0 grid has 256 extra blocks (bid >= nwg_gemm) that finish qt:
//   qt = (Σ partial sums)/64 @ Wq * scale, fragment-packed bf16.
// TERMS=1: ah*bh | 4: ah*bh + ah*bl
template <int EPI, int MT, int NT, int TERMS>
__global__ __launch_bounds__(256) void mfma_gemm(
    const ushort_t* __restrict__ Ahi, const ushort_t* __restrict__ Alo,
    const ushort_t* __restrict__ Bthi, const ushort_t* __restrict__ Btlo,
    const float* __restrict__ bias, float* __restrict__ C,
    ushort_t* __restrict__ kh, ushort_t* __restrict__ vP,
    ushort_t* __restrict__ gatesP,
    const float* __restrict__ Wq, const float* __restrict__ ps,
    ushort_t* __restrict__ qPh, int nwg_gemm, int gridn) {
    constexpr int BM = MT * 32, BN = NT * 32;
    constexpr int ASZ = BM * 32 * 2;
    constexpr int BSZ = BN * 32 * 2;
    constexpr bool HAS_AL = (TERMS == 2 || TERMS == 3);
    constexpr bool HAS_BL = (TERMS == 3 || TERMS == 4);
    constexpr int AL_OFF = 2 * ASZ;
    constexpr int BH_OFF = AL_OFF + (HAS_AL ? 2 * ASZ : 0);
    constexpr int BL_OFF = BH_OFF + 2 * BSZ;
    constexpr int SMEM_BYTES = BL_OFF + (HAS_BL ? 2 * BSZ : 0);
    __shared__ __align__(16) char smem[SMEM_BYTES];
    char* aH = smem;
    char* aL = smem + AL_OFF;
    char* bH = smem + BH_OFF;
    char* bL = smem + BL_OFF;

    const int t = threadIdx.x;
    const int bid = blockIdx.x;

    if (EPI == 0 && bid >= nwg_gemm) {        // ---- qt finish ----
        float* xrow = (float*)smem;
        int i = bid - nwg_gemm;               // 0..255
        float s4 = ps[((size_t)0 * 256 + i) * 256 + t] +
                   ps[((size_t)1 * 256 + i) * 256 + t] +
                   ps[((size_t)2 * 256 + i) * 256 + t] +
                   ps[((size_t)3 * 256 + i) * 256 + t];
        xrow[t] = s4 * (1.0f / 64.0f);
        __syncthreads();
        float s = 0.f;
        for (int k = 0; k < 256; k++)
            s = fmaf(xrow[k], Wq[(size_t)k * 256 + t], s);
        s *= 0.17677669529663687f;   // 1/sqrt(32)
        int h = t >> 5, d = t & 31, lg = d >> 3, e = d & 7;
        int g = i >> 4, lr = i & 15;
        int a = (((h * 16 + g) * 4 + lg) * 16 + lr) * 8 + e;
        qPh[a] = f2bf(s);
        return;
    }

    const int cpx = nwg_gemm >> 3;
    const int sid = (bid & 7) * cpx + (bid >> 3);   // XCD-chunked
    const int m0 = (sid / gridn) * BM;
    const int n0 = (sid % gridn) * BN;
    const int wid = t >> 6, lane = t & 63;
    const int wr = wid >> 1, wc = wid & 1;
    const int lr = lane & 15, lg = lane >> 4;

    auto STAGE = [&](int d, int ks) {
        const int k0 = ks * 32;
#pragma unroll
        for (int it = 0; it < BM / 64; ++it) {
            int c = t + it * 256;
            int row = c >> 2, sub = c & 3;
            size_t ga = (size_t)(m0 + row) * 256 + k0 + sub * 8;
            gl2lds16(Ahi + ga, aH + d * ASZ + c * 16);
            if constexpr (HAS_AL)
                gl2lds16(Alo + ga, aL + d * ASZ + c * 16);
        }
#pragma unroll
        for (int it = 0; it < BN / 64; ++it) {
            int c = t + it * 256;
            int row = c >> 2, sub = c & 3;
            size_t gb = (size_t)(n0 + row) * 256 + k0 + sub * 8;
            gl2lds16(Bthi + gb, bH + d * BSZ + c * 16);
            if constexpr (HAS_BL)
                gl2lds16(Btlo + gb, bL + d * BSZ + c * 16);
        }
    };

    f32x4 acc[MT][NT] = {};

    STAGE(0, 0);
    asm volatile("s_waitcnt vmcnt(0)" ::: "memory");
    __syncthreads();

    int cur = 0;
    for (int ks = 0; ks < 8; ++ks) {
        if (ks < 7) STAGE(cur ^ 1, ks + 1);

        const ushort_t* Ap = (const ushort_t*)(aH + cur * ASZ);
        const ushort_t* ALp = (const ushort_t*)(aL + cur * ASZ);
        const ushort_t* Bp = (const ushort_t*)(bH + cur * BSZ);
        const ushort_t* BLp = (const ushort_t*)(bL + cur * BSZ);

        short8v ah[MT], al[MT], bh[NT], bl[NT];
#pragma unroll
        for (int m = 0; m < MT; m++) {
            int off = (wr * (MT * 16) + m * 16 + lr) * 32 + lg * 8;
            ah[m] = *(const short8v*)&Ap[off];
            if constexpr (HAS_AL) al[m] = *(const short8v*)&ALp[off];
        }
#pragma unroll
        for (int n = 0; n < NT; n++) {
            int off = (wc * (NT * 16) + n * 16 + lr) * 32 + lg * 8;
            bh[n] = *(const short8v*)&Bp[off];
            if constexpr (HAS_BL) bl[n] = *(const short8v*)&BLp[off];
        }
#pragma unroll
        for (int m = 0; m < MT; m++)
#pragma unroll
            for (int n = 0; n < NT; n++) {
                acc[m][n] = __builtin_amdgcn_mfma_f32_16x16x32_bf16(
                    ah[m], bh[n], acc[m][n], 0, 0, 0);
                if constexpr (HAS_AL)
                    acc[m][n] = __builtin_amdgcn_mfma_f32_16x16x32_bf16(
                        al[m], bh[n], acc[m][n], 0, 0, 0);
                if constexpr (HAS_BL)
                    acc[m][n] = __builtin_amdgcn_mfma_f32_16x16x32_bf16(
                        ah[m], bl[n], acc[m][n], 0, 0, 0);
            }

        if (ks < 7) {
            asm volatile("s_waitcnt vmcnt(0)" ::: "memory");
            __syncthreads();
        }
        cur ^= 1;
    }

#pragma unroll
    for (int m = 0; m < MT; m++)
#pragma unroll
        for (int n = 0; n < NT; n++) {
            int gr0 = m0 + wr * (MT * 16) + m * 16 + lg * 4;
            int gc = n0 + wc * (NT * 16) + n * 16 + lr;
            if (EPI == 0) {
                if (gc < 256) {          // K fragment-packed, hi only
                    int hh_ = gc >> 5, dk = gc & 31;
                    int lgk = dk >> 3, ek = dk & 7;
#pragma unroll
                    for (int r = 0; r < 4; r++) {
                        int gr = gr0 + r;
                        int bb = gr >> 8, j = gr & 255;
                        int jt = j >> 6, mfk = (j >> 4) & 3, lrk = j & 15;
                        size_t a =
                            (((((size_t)(bb * 8 + hh_) * 4 + jt) * 4 + mfk) * 4
                              + lgk) * 16 + lrk) * 8 + ek;
                        kh[a] = f2bf(acc[m][n][r]);
                    }
                } else if (gc < 512) {   // V^T fragment-packed hi only
                    int cc = gc - 256;
                    int hh_ = cc >> 5, dv = cc & 31;
                    int mfv = dv >> 4, lrv = dv & 15;
                    int gr = gr0;
                    int bb = gr >> 8, j = gr & 255;
                    int jt = j >> 6, hbv = (j >> 5) & 1;
                    int lgv = (j >> 3) & 3, ev = j & 7;
                    size_t a =
                        ((((((size_t)(bb * 8 + hh_) * 4 + jt) * 2 + hbv) * 2
                           + mfv) * 4 + lgv) * 16 + lrv) * 8 + ev;
                    ushort4 hv;
                    hv.x = f2bf(acc[m][n][0]);
                    hv.y = f2bf(acc[m][n][1]);
                    hv.z = f2bf(acc[m][n][2]);
                    hv.w = f2bf(acc[m][n][3]);
                    *(ushort4*)(vP + a) = hv;
                } else {                 // gates bf16, attn-epilogue-fragment order
                    int c = gc - 512;
                    int hh_ = c >> 5, d = c & 31;
                    int mdv = d >> 4, lga = (d >> 2) & 3, ev = d & 3;
#pragma unroll
                    for (int r = 0; r < 4; r++) {
                        int gr = gr0 + r;
                        int bb = gr >> 8, i = gr & 255;
                        int i16 = i >> 4, lra = i & 15;
                        size_t a =
                            ((((size_t)(bb * 8 + hh_) * 16 + i16) * 2 + mdv)
                             * 64 + lga * 16 + lra) * 4 + ev;
                        float v = acc[m][n][r];
                        float g = 1.f / (1.f + __expf(-(v + bias[gc - 512])));
                        gatesP[a] = f2bf(g);
                    }
                }
            } else {
#pragma unroll
                for (int r = 0; r < 4; r++)
                    C[(size_t)(gr0 + r) * 256 + gc] = acc[m][n][r] + bias[gc];
            }
        }
}

// ---------------------------------------------------------------------------
// Per-wave online MFMA flash attention, 16 q-rows per wave.
// Depth-2 prefetch for K, bias AND V; bit-packed mask in registers;
// gates hoisted to prologue; single LDS round-trip per tile; setprio.
__global__ __launch_bounds__(256) void attn_mfma_kernel(
    const ushort_t* __restrict__ qPh, const ushort_t* __restrict__ kh,
    const ushort_t* __restrict__ vP, const ushort_t* __restrict__ gatesP,
    const float* __restrict__ biasP, const uint_t* __restrict__ maskb,
    ushort_t* __restrict__ atthi) {
    __shared__ __align__(16) ushort_t Pb[4][16 * 88];   // stride 88: 2-way banks
    const int bid = blockIdx.x;
    const int sid = ((bid & 7) << 8) | (bid >> 3);  // 2048 = 8*256
    const int b = sid >> 5;
    const int h = (sid >> 2) & 7;
    const int qq = sid & 3;
    const int t = threadIdx.x;
    const int w = t >> 6, lane = t & 63;
    const int lr = lane & 15, lg = lane >> 4;
    const int i0 = qq * 64 + w * 16;
    const int i16 = qq * 4 + w;
    ushort_t* pbh = Pb[w];

    // block-uniform mask words (scalar loads)
    uint_t mw[8];
#pragma unroll
    for (int k = 0; k < 8; k++) mw[k] = maskb[b * 8 + k];
    const uint_t mi = (mw[i0 >> 5] >> ((i0 & 31) + lr)) & 1u;

    short8v qf;
    {
        size_t off = ((((size_t)h * 16 + i16) * 4 + lg) * 16 + lr) * 8;
        qf = *(const short8v*)(qPh + off);
    }
    // gates hoisted (coalesced)
    uint2 gva, gvb;
    {
        size_t ga = ((((size_t)(b * 8 + h) * 16 + i16) * 2 + 0) * 64 + lane) * 4;
        gva = *(const uint2*)(gatesP + ga);
        gvb = *(const uint2*)(gatesP + ga + 256);
    }

    const float* bbase = biasP +
        (size_t)(h * 256 + (i16 >> 1) * 32 + (i16 & 1) * 4) * 256 +
        (size_t)lane * 4;

    float m_run = NEG_MAX, l_run = 0.f;
    f32x4 acc_o[2] = {};

    // prefetch tile 0: K + bias + V
    short8v kf[2][4];
    float4 bf[2][4];
    short8v vf[2][2][2];   // [buf][hb][mv]
#pragma unroll
    for (int mf = 0; mf < 4; mf++) {
        size_t off = ((((size_t)(b * 8 + h) * 4 + 0) * 4 + mf) * 4 + lg);
        kf[0][mf] = *(const short8v*)(kh + (off * 16 + lr) * 8);
        bf[0][mf] = *(const float4*)(bbase + (size_t)mf * 256);
    }
#pragma unroll
    for (int hb = 0; hb < 2; hb++)
#pragma unroll
        for (int mv = 0; mv < 2; mv++) {
            size_t off = ((((((size_t)(b * 8 + h) * 4 + 0) * 2 + hb) * 2
                           + mv) * 4 + lg) * 16 + lr) * 8;
            vf[0][hb][mv] = *(const short8v*)(vP + off);
        }

#pragma unroll
    for (int jt = 0; jt < 4; ++jt) {
        const int cur = jt & 1, nxt = cur ^ 1;
        if (jt < 3) {
#pragma unroll
            for (int mf = 0; mf < 4; mf++) {
                size_t off = ((((size_t)(b * 8 + h) * 4 + (jt + 1)) * 4 + mf)
                              * 4 + lg);
                kf[nxt][mf] = *(const short8v*)(kh + (off * 16 + lr) * 8);
                bf[nxt][mf] = *(const float4*)(bbase +
                                               (size_t)((jt + 1) * 8 + mf) * 256);
            }
#pragma unroll
            for (int hb = 0; hb < 2; hb++)
#pragma unroll
                for (int mv = 0; mv < 2; mv++) {
                    size_t off = ((((((size_t)(b * 8 + h) * 4 + (jt + 1)) * 2
                                    + hb) * 2 + mv) * 4 + lg) * 16 + lr) * 8;
                    vf[nxt][hb][mv] = *(const short8v*)(vP + off);
                }
        }

        // S^T = K * Q^T (1-term)
        f32x4 s[4];
        __builtin_amdgcn_s_setprio(1);
#pragma unroll
        for (int mf = 0; mf < 4; mf++) {
            f32x4 a = {};
            s[mf] = __builtin_amdgcn_mfma_f32_16x16x32_bf16(
                kf[cur][mf], qf, a, 0, 0, 0);
        }
        __builtin_amdgcn_s_setprio(0);

        // bias + mask (bit-packed, register-resident)
#pragma unroll
        for (int mf = 0; mf < 4; mf++) {
            float4 bv = bf[cur][mf];
            uint_t bits = (mw[jt * 2 + (mf >> 1)] >> (((mf & 1) << 4) + (lg << 2)));
            s[mf][0] = ((mi & bits) & 1u)        ? s[mf][0] + bv.x : NEG_MAX;
            s[mf][1] = ((mi & (bits >> 1)) & 1u) ? s[mf][1] + bv.y : NEG_MAX;
            s[mf][2] = ((mi & (bits >> 2)) & 1u) ? s[mf][2] + bv.z : NEG_MAX;
            s[mf][3] = ((mi & (bits >> 3)) & 1u) ? s[mf][3] + bv.w : NEG_MAX;
        }

        // online softmax
        float tm = s[0][0];
#pragma unroll
        for (int mf = 0; mf < 4; mf++)
#pragma unroll
            for (int r = 0; r < 4; r++) tm = fmaxf(tm, s[mf][r]);
        tm = fmaxf(tm, __shfl_xor(tm, 16));
        tm = fmaxf(tm, __shfl_xor(tm, 32));
        float mnew = fmaxf(m_run, tm);
        float corr = __expf(m_run - mnew);
        m_run = mnew;
#pragma unroll
        for (int md = 0; md < 2; md++)
#pragma unroll
            for (int r = 0; r < 4; r++) acc_o[md][r] *= corr;
        float ls = 0.f;
#pragma unroll
        for (int mf = 0; mf < 4; mf++)
#pragma unroll
            for (int r = 0; r < 4; r++) {
                float wv = __expf(s[mf][r] - mnew);
                s[mf][r] = wv;
                ls += wv;
            }
        ls += __shfl_xor(ls, 16);
        ls += __shfl_xor(ls, 32);
        l_run = l_run * corr + ls;

        // PV: pack all 64 j-cols to LDS, single wait, 4 MFMAs
#pragma unroll
        for (int mf = 0; mf < 4; mf++) {
            uint2 hv;
            hv.x = (uint_t)f2bf(s[mf][0]) | ((uint_t)f2bf(s[mf][1]) << 16);
            hv.y = (uint_t)f2bf(s[mf][2]) | ((uint_t)f2bf(s[mf][3]) << 16);
            *(uint2*)(pbh + lr * 88 + mf * 16 + lg * 4) = hv;
        }
        asm volatile("s_waitcnt lgkmcnt(0)" ::: "memory");
        __builtin_amdgcn_sched_barrier(0);
        short8v ph0 = *(const short8v*)(pbh + lr * 88 + lg * 8);
        short8v ph1 = *(const short8v*)(pbh + lr * 88 + 32 + lg * 8);
        __builtin_amdgcn_s_setprio(1);
        acc_o[0] = __builtin_amdgcn_mfma_f32_16x16x32_bf16(
            vf[cur][0][0], ph0, acc_o[0], 0, 0, 0);
        acc_o[1] = __builtin_amdgcn_mfma_f32_16x16x32_bf16(
            vf[cur][0][1], ph0, acc_o[1], 0, 0, 0);
        acc_o[0] = __builtin_amdgcn_mfma_f32_16x16x32_bf16(
            vf[cur][1][0], ph1, acc_o[0], 0, 0, 0);
        acc_o[1] = __builtin_amdgcn_mfma_f32_16x16x32_bf16(
            vf[cur][1][1], ph1, acc_o[1], 0, 0, 0);
        __builtin_amdgcn_s_setprio(0);
    }

    // epilogue: O = acc/l * gate (preloaded), bf16 hi only
    float invl = 1.0f / l_run;
#pragma unroll
    for (int md = 0; md < 2; md++) {
        uint2 gv = (md == 0) ? gva : gvb;
        float g0 = bf2f((ushort_t)(gv.x & 0xffff));
        float g1 = bf2f((ushort_t)(gv.x >> 16));
        float g2 = bf2f((ushort_t)(gv.y & 0xffff));
        float g3 = bf2f((ushort_t)(gv.y >> 16));
        int i = i0 + lr;
        int d0 = md * 16 + lg * 4;
        size_t base = ((size_t)(b * 256 + i)) * 256 + h * 32 + d0;
        ushort4 hh;
        hh.x = f2bf(acc_o[md][0] * invl * g0);
        hh.y = f2bf(acc_o[md][1] * invl * g1);
        hh.z = f2bf(acc_o[md][2] * invl * g2);
        hh.w = f2bf(acc_o[md][3] * invl * g3);
        *(ushort4*)(atthi + base) = hh;
    }
}

// ---------------------------------------------------------------------------
extern "C" void kernel_launch(void* const* d_in, const int* in_sizes, int n_in,
                              void* d_out, int out_size, void* d_ws, size_t ws_size,
                              hipStream_t stream) {
    const float* x    = (const float*)d_in[0];
    const unsigned char* mraw = (const unsigned char*)d_in[1];
    const float* bias = (const float*)d_in[2];
    const float* Wq   = (const float*)d_in[3];
    const float* Wkv  = (const float*)d_in[4];
    const float* Wg   = (const float*)d_in[5];
    const float* bg   = (const float*)d_in[6];
    const float* Wo   = (const float*)d_in[7];
    const float* bo   = (const float*)d_in[8];

    float* ws = (float*)d_ws;
    ushort_t* kh     = (ushort_t*)(ws + OFF_KH);
    ushort_t* vP     = (ushort_t*)(ws + OFF_VP);
    ushort_t* gatesP = (ushort_t*)(ws + OFF_GATES);
    ushort_t* xhi    = (ushort_t*)(ws + OFF_XHI);
    ushort_t* atthi  = (ushort_t*)(ws + OFF_ATTHI);  // aliases xhi (dead)
    ushort_t* bthi   = (ushort_t*)(ws + OFF_BTHI);
    ushort_t* btlo   = (ushort_t*)(ws + OFF_BTLO);
    ushort_t* qPh    = (ushort_t*)(ws + OFF_QTH);
    float*    biasP  = ws + OFF_BIASP;
    uint_t*   maskb  = (uint_t*)(ws + OFF_MASK);
    float*    ps     = ws + OFF_PSUM;

    hipLaunchKernelGGL(prep_kernel, dim3(2561), dim3(256), 0, stream,
                       x, mraw, bias, Wkv, Wg, Wo,
                       xhi, maskb, bthi, btlo, biasP, ps);
    // proj: 768 gemm tiles + 256 qt-finish blocks; 128x128, 1-term, dbuf
    hipLaunchKernelGGL((mfma_gemm<0, 4, 4, 1>), dim3(1024), dim3(256), 0, stream,
                       xhi, xhi, bthi, btlo, bg, (float*)nullptr,
                       kh, vP, gatesP, Wq, ps, qPh, 768, 6);
    hipLaunchKernelGGL(attn_mfma_kernel, dim3(2048), dim3(256), 0, stream,
                       qPh, kh, vP, gatesP, biasP, maskb, atthi);
    // out = att @ Wo + bo : TERMS=4 (ah*bh + ah*bl), 64x64 tiles, 1024 blocks
    hipLaunchKernelGGL((mfma_gemm<1, 2, 2, 4>), dim3(1024), dim3(256), 0, stream,
                       atthi, atthi, bthi + 768 * 256, btlo + 768 * 256, bo,
                       (float*)d_out, nullptr, nullptr, nullptr,
                       (const float*)nullptr, (const float*)nullptr,
                       (ushort_t*)nullptr, 1024, 4);
}

// Round 21
// 67.765 us; speedup vs baseline: 1.0739x; 1.0739x over previous
//
#include <hip/hip_runtime.h>
#include <math.h>

typedef unsigned short ushort_t;
typedef unsigned int uint_t;
typedef __attribute__((ext_vector_type(8))) short short8v;   // 8 bf16 (4 VGPR)
typedef __attribute__((ext_vector_type(4))) float f32x4;

#define NEG_MAX (-3.402823466e+38f)

// -------- ws layout (float offsets) --------
#define OFF_KH    0
#define OFF_VP    4194304
#define OFF_GATES 6291456
#define OFF_XHI   8388608
#define OFF_ATTHI OFF_XHI                  // aliases xhi (dead after proj)
#define OFF_BTHI  12582912
#define OFF_BTLO  12713984
#define OFF_QTH   12845056
#define OFF_BIASP 12976128
#define OFF_MASK  13500416

// ---------------------------------------------------------------------------
__device__ __forceinline__ ushort_t f2bf(float x) {
    uint_t u = __float_as_uint(x);
    u = (u + 0x7fffu + ((u >> 16) & 1u)) >> 16;   // RNE
    return (ushort_t)u;
}
__device__ __forceinline__ float bf2f(ushort_t u) {
    return __uint_as_float(((uint_t)u) << 16);
}
__device__ __forceinline__ void gl2lds16(const void* g, void* l) {
    typedef const __attribute__((address_space(1))) uint32_t* gptr_t;
    typedef __attribute__((address_space(3))) uint32_t* lptr_t;
    __builtin_amdgcn_global_load_lds((gptr_t)(uintptr_t)g,
                                     (lptr_t)(uintptr_t)l, 16, 0, 0);
}

// ---------------------------------------------------------------------------
// Fused prep kernel. Block ranges:
// [0,1) mask bitpack | [1,1025) wsplit | [1025,1537) bias_prepack
// [1537,1793) qt = mean(x)@Wq  + x->bf16 split (x read ONCE)
__global__ __launch_bounds__(256) void prep_kernel(
    const float* __restrict__ x, const unsigned char* __restrict__ mraw,
    const float* __restrict__ bias, const float* __restrict__ Wkv,
    const float* __restrict__ Wg, const float* __restrict__ Wo,
    const float* __restrict__ Wq,
    ushort_t* __restrict__ xhi,
    uint_t* __restrict__ maskb,
    ushort_t* __restrict__ bthi, ushort_t* __restrict__ btlo,
    float* __restrict__ biasP, ushort_t* __restrict__ qPh) {
    __shared__ int cnt[256];
    __shared__ float xrow[256];
    const int bid = blockIdx.x, t = threadIdx.x;
    if (bid < 1) {                            // ---- mask bitpack ----
        int c = 0;
        for (int i = t; i < 4096; i += 256)
            if ((i & 3) != 0 && mraw[i] != 0) c++;
        cnt[t] = c;
        __syncthreads();
        for (int s = 128; s > 0; s >>= 1) {
            if (t < s) cnt[t] += cnt[t + s];
            __syncthreads();
        }
        int isBool = cnt[0] > 16;
        const int* mi32 = (const int*)mraw;
#pragma unroll
        for (int wq = 0; wq < 2; wq++) {
            int widx = t * 2 + wq;            // 0..511 = b*8 + (j>>5)
            int j0 = widx * 32;
            uint_t wordv = 0;
            if (isBool) {
                for (int k = 0; k < 32; k++)
                    wordv |= (mraw[j0 + k] ? 1u : 0u) << k;
            } else {
                for (int k = 0; k < 32; k++)
                    wordv |= (mi32[j0 + k] ? 1u : 0u) << k;
            }
            maskb[widx] = wordv;
        }
    } else if (bid < 1025) {                  // ---- wsplit ----
        int idx = (bid - 1) * 256 + t;
        int n = idx >> 8, k = idx & 255;
        float v;
        if (n < 512)      v = Wkv[(size_t)k * 512 + n];
        else if (n < 768) v = Wg[(size_t)k * 256 + (n - 512)];
        else              v = Wo[(size_t)k * 256 + (n - 768)];
        ushort_t h = f2bf(v);
        bthi[idx] = h;
        btlo[idx] = f2bf(v - bf2f(h));
    } else if (bid < 1537) {                  // ---- bias prepack ----
        int idx = (bid - 1025) * 256 + t;     // 0..131071
        int lane = idx & 63, g2 = idx >> 6;   // g2 0..2047
        int mf = g2 & 3, nf = (g2 >> 2) & 1, jt = (g2 >> 3) & 3;
        int iq = (g2 >> 5) & 7, h = g2 >> 8;
        int lr = lane & 15, lg = lane >> 4;
        float4 v = *(const float4*)(bias +
            (size_t)(h * 256 + iq * 32 + nf * 16 + lr) * 256 +
            jt * 64 + mf * 16 + lg * 4);
        *(float4*)(biasP + (size_t)idx * 4) = v;
    } else {                                  // ---- qt + x split ----
        int i = bid - 1537;                   // 0..255 (sequence row)
        float ssum = 0.f;
#pragma unroll 8
        for (int b8 = 0; b8 < 64; b8++) {
            size_t idx = (size_t)(b8 * 256 + i) * 256 + t;
            float v = x[idx];
            xhi[idx] = f2bf(v);
            ssum += v;
        }
        xrow[t] = ssum * (1.0f / 64.0f);
        __syncthreads();
        float s = 0.f;
        for (int k = 0; k < 256; k++)
            s = fmaf(xrow[k], Wq[(size_t)k * 256 + t], s);
        s *= 0.17677669529663687f;   // 1/sqrt(32)
        int h = t >> 5, d = t & 31, lg = d >> 3, e = d & 7;
        int g = i >> 4, lr = i & 15;
        int a = (((h * 16 + g) * 4 + lg) * 16 + lr) * 8 + e;
        qPh[a] = f2bf(s);
    }
}

// ---------------------------------------------------------------------------
// Double-buffered MFMA split-bf16 GEMM, 1-D XCD-swizzled grid.
// TERMS=1: ah*bh | 2: + al*bh | 3: + al*bh + ah*bl | 4: ah*bh + ah*bl
template <int EPI, int MT, int NT, int TERMS>
__global__ __launch_bounds__(256) void mfma_gemm(
    const ushort_t* __restrict__ Ahi, const ushort_t* __restrict__ Alo,
    const ushort_t* __restrict__ Bthi, const ushort_t* __restrict__ Btlo,
    const float* __restrict__ bias, float* __restrict__ C,
    ushort_t* __restrict__ kh, ushort_t* __restrict__ vP,
    ushort_t* __restrict__ gatesP, int gridn) {
    constexpr int BM = MT * 32, BN = NT * 32;
    constexpr int ASZ = BM * 32 * 2;
    constexpr int BSZ = BN * 32 * 2;
    constexpr bool HAS_AL = (TERMS == 2 || TERMS == 3);
    constexpr bool HAS_BL = (TERMS == 3 || TERMS == 4);
    constexpr int AL_OFF = 2 * ASZ;
    constexpr int BH_OFF = AL_OFF + (HAS_AL ? 2 * ASZ : 0);
    constexpr int BL_OFF = BH_OFF + 2 * BSZ;
    constexpr int SMEM_BYTES = BL_OFF + (HAS_BL ? 2 * BSZ : 0);
    __shared__ __align__(16) char smem[SMEM_BYTES];
    char* aH = smem;
    char* aL = smem + AL_OFF;
    char* bH = smem + BH_OFF;
    char* bL = smem + BL_OFF;

    const int t = threadIdx.x;
    const int nwg = gridDim.x, cpx = nwg >> 3;
    const int bid = blockIdx.x;
    const int sid = (bid & 7) * cpx + (bid >> 3);   // XCD-chunked
    const int m0 = (sid / gridn) * BM;
    const int n0 = (sid % gridn) * BN;
    const int wid = t >> 6, lane = t & 63;
    const int wr = wid >> 1, wc = wid & 1;
    const int lr = lane & 15, lg = lane >> 4;

    auto STAGE = [&](int d, int ks) {
        const int k0 = ks * 32;
#pragma unroll
        for (int it = 0; it < BM / 64; ++it) {
            int c = t + it * 256;
            int row = c >> 2, sub = c & 3;
            size_t ga = (size_t)(m0 + row) * 256 + k0 + sub * 8;
            gl2lds16(Ahi + ga, aH + d * ASZ + c * 16);
            if constexpr (HAS_AL)
                gl2lds16(Alo + ga, aL + d * ASZ + c * 16);
        }
#pragma unroll
        for (int it = 0; it < BN / 64; ++it) {
            int c = t + it * 256;
            int row = c >> 2, sub = c & 3;
            size_t gb = (size_t)(n0 + row) * 256 + k0 + sub * 8;
            gl2lds16(Bthi + gb, bH + d * BSZ + c * 16);
            if constexpr (HAS_BL)
                gl2lds16(Btlo + gb, bL + d * BSZ + c * 16);
        }
    };

    f32x4 acc[MT][NT] = {};

    STAGE(0, 0);
    asm volatile("s_waitcnt vmcnt(0)" ::: "memory");
    __syncthreads();

    int cur = 0;
    for (int ks = 0; ks < 8; ++ks) {
        if (ks < 7) STAGE(cur ^ 1, ks + 1);

        const ushort_t* Ap = (const ushort_t*)(aH + cur * ASZ);
        const ushort_t* ALp = (const ushort_t*)(aL + cur * ASZ);
        const ushort_t* Bp = (const ushort_t*)(bH + cur * BSZ);
        const ushort_t* BLp = (const ushort_t*)(bL + cur * BSZ);

        short8v ah[MT], al[MT], bh[NT], bl[NT];
#pragma unroll
        for (int m = 0; m < MT; m++) {
            int off = (wr * (MT * 16) + m * 16 + lr) * 32 + lg * 8;
            ah[m] = *(const short8v*)&Ap[off];
            if constexpr (HAS_AL) al[m] = *(const short8v*)&ALp[off];
        }
#pragma unroll
        for (int n = 0; n < NT; n++) {
            int off = (wc * (NT * 16) + n * 16 + lr) * 32 + lg * 8;
            bh[n] = *(const short8v*)&Bp[off];
            if constexpr (HAS_BL) bl[n] = *(const short8v*)&BLp[off];
        }
#pragma unroll
        for (int m = 0; m < MT; m++)
#pragma unroll
            for (int n = 0; n < NT; n++) {
                acc[m][n] = __builtin_amdgcn_mfma_f32_16x16x32_bf16(
                    ah[m], bh[n], acc[m][n], 0, 0, 0);
                if constexpr (HAS_AL)
                    acc[m][n] = __builtin_amdgcn_mfma_f32_16x16x32_bf16(
                        al[m], bh[n], acc[m][n], 0, 0, 0);
                if constexpr (HAS_BL)
                    acc[m][n] = __builtin_amdgcn_mfma_f32_16x16x32_bf16(
                        ah[m], bl[n], acc[m][n], 0, 0, 0);
            }

        if (ks < 7) {
            asm volatile("s_waitcnt vmcnt(0)" ::: "memory");
            __syncthreads();
        }
        cur ^= 1;
    }

#pragma unroll
    for (int m = 0; m < MT; m++)
#pragma unroll
        for (int n = 0; n < NT; n++) {
            int gr0 = m0 + wr * (MT * 16) + m * 16 + lg * 4;
            int gc = n0 + wc * (NT * 16) + n * 16 + lr;
            if (EPI == 0) {
                if (gc < 256) {          // K fragment-packed, hi only
                    int hh_ = gc >> 5, dk = gc & 31;
                    int lgk = dk >> 3, ek = dk & 7;
#pragma unroll
                    for (int r = 0; r < 4; r++) {
                        int gr = gr0 + r;
                        int bb = gr >> 8, j = gr & 255;
                        int jt = j >> 6, mfk = (j >> 4) & 3, lrk = j & 15;
                        size_t a =
                            (((((size_t)(bb * 8 + hh_) * 4 + jt) * 4 + mfk) * 4
                              + lgk) * 16 + lrk) * 8 + ek;
                        kh[a] = f2bf(acc[m][n][r]);
                    }
                } else if (gc < 512) {   // V^T fragment-packed hi only
                    int cc = gc - 256;
                    int hh_ = cc >> 5, dv = cc & 31;
                    int mfv = dv >> 4, lrv = dv & 15;
                    int gr = gr0;
                    int bb = gr >> 8, j = gr & 255;
                    int jt = j >> 6, hbv = (j >> 5) & 1;
                    int lgv = (j >> 3) & 3, ev = j & 7;
                    size_t a =
                        ((((((size_t)(bb * 8 + hh_) * 4 + jt) * 2 + hbv) * 2
                           + mfv) * 4 + lgv) * 16 + lrv) * 8 + ev;
                    ushort4 hv;
                    hv.x = f2bf(acc[m][n][0]);
                    hv.y = f2bf(acc[m][n][1]);
                    hv.z = f2bf(acc[m][n][2]);
                    hv.w = f2bf(acc[m][n][3]);
                    *(ushort4*)(vP + a) = hv;
                } else {                 // gates bf16, attn-epilogue-fragment order
                    int c = gc - 512;
                    int hh_ = c >> 5, d = c & 31;
                    int mdv = d >> 4, lga = (d >> 2) & 3, ev = d & 3;
#pragma unroll
                    for (int r = 0; r < 4; r++) {
                        int gr = gr0 + r;
                        int bb = gr >> 8, i = gr & 255;
                        int i16 = i >> 4, lra = i & 15;
                        size_t a =
                            ((((size_t)(bb * 8 + hh_) * 16 + i16) * 2 + mdv)
                             * 64 + lga * 16 + lra) * 4 + ev;
                        float v = acc[m][n][r];
                        float g = 1.f / (1.f + __expf(-(v + bias[gc - 512])));
                        gatesP[a] = f2bf(g);
                    }
                }
            } else {
#pragma unroll
                for (int r = 0; r < 4; r++)
                    C[(size_t)(gr0 + r) * 256 + gc] = acc[m][n][r] + bias[gc];
            }
        }
}

// ---------------------------------------------------------------------------
// Per-wave online MFMA flash attention, 16 q-rows per wave.
// SMALL-BODY variant: jt loop NOT unrolled, direct per-tile loads, minimal
// register footprint -> high occupancy; TLP hides load latency.
__global__ __launch_bounds__(256) void attn_mfma_kernel(
    const ushort_t* __restrict__ qPh, const ushort_t* __restrict__ kh,
    const ushort_t* __restrict__ vP, const ushort_t* __restrict__ gatesP,
    const float* __restrict__ biasP, const uint_t* __restrict__ maskb,
    ushort_t* __restrict__ atthi) {
    __shared__ __align__(16) ushort_t Pb[4][16 * 88];   // stride 88: 2-way banks
    const int bid = blockIdx.x;
    const int sid = ((bid & 7) << 8) | (bid >> 3);  // 2048 = 8*256
    const int b = sid >> 5;
    const int h = (sid >> 2) & 7;
    const int qq = sid & 3;
    const int t = threadIdx.x;
    const int w = t >> 6, lane = t & 63;
    const int lr = lane & 15, lg = lane >> 4;
    const int i0 = qq * 64 + w * 16;
    const int i16 = qq * 4 + w;
    ushort_t* pbh = Pb[w];

    // block-uniform mask words (scalar loads)
    uint_t mw[8];
#pragma unroll
    for (int k = 0; k < 8; k++) mw[k] = maskb[b * 8 + k];
    const uint_t mi = (mw[i0 >> 5] >> ((i0 & 31) + lr)) & 1u;

    short8v qf;
    {
        size_t off = ((((size_t)h * 16 + i16) * 4 + lg) * 16 + lr) * 8;
        qf = *(const short8v*)(qPh + off);
    }
    // gates hoisted (coalesced)
    uint2 gva, gvb;
    {
        size_t ga = ((((size_t)(b * 8 + h) * 16 + i16) * 2 + 0) * 64 + lane) * 4;
        gva = *(const uint2*)(gatesP + ga);
        gvb = *(const uint2*)(gatesP + ga + 256);
    }

    const float* bbase = biasP +
        (size_t)(h * 256 + (i16 >> 1) * 32 + (i16 & 1) * 4) * 256 +
        (size_t)lane * 4;
    // K element addr: ((b*8+h)*64 + jt*16 + mf*4 + lg)*128 + lr*8
    const ushort_t* kbase = kh +
        ((size_t)(b * 8 + h) * 64 + lg) * 128 + lr * 8;
    // V element addr: ((b*8+h)*64 + jt*16 + (hb*2+mv)*4 + lg)*128 + lr*8
    const ushort_t* vbase = vP +
        ((size_t)(b * 8 + h) * 64 + lg) * 128 + lr * 8;

    float m_run = NEG_MAX, l_run = 0.f;
    f32x4 acc_o[2] = {};

#pragma unroll 1
    for (int jt = 0; jt < 4; ++jt) {
        // direct loads for this tile (no prefetch buffers)
        short8v kf[4];
        float4 bf[4];
        short8v vf[4];   // [hb*2+mv]
#pragma unroll
        for (int mf = 0; mf < 4; mf++) {
            kf[mf] = *(const short8v*)(kbase + ((size_t)jt * 16 + mf * 4) * 128);
            bf[mf] = *(const float4*)(bbase + (size_t)(jt * 8 + mf) * 256);
        }
#pragma unroll
        for (int hm = 0; hm < 4; hm++)
            vf[hm] = *(const short8v*)(vbase + ((size_t)jt * 16 + hm * 4) * 128);

        // S^T = K * Q^T (1-term)
        f32x4 s[4];
        __builtin_amdgcn_s_setprio(1);
#pragma unroll
        for (int mf = 0; mf < 4; mf++) {
            f32x4 a = {};
            s[mf] = __builtin_amdgcn_mfma_f32_16x16x32_bf16(
                kf[mf], qf, a, 0, 0, 0);
        }
        __builtin_amdgcn_s_setprio(0);

        // bias + mask (bit-packed, register-resident)
#pragma unroll
        for (int mf = 0; mf < 4; mf++) {
            float4 bv = bf[mf];
            uint_t bits = (mw[jt * 2 + (mf >> 1)] >> (((mf & 1) << 4) + (lg << 2)));
            s[mf][0] = ((mi & bits) & 1u)        ? s[mf][0] + bv.x : NEG_MAX;
            s[mf][1] = ((mi & (bits >> 1)) & 1u) ? s[mf][1] + bv.y : NEG_MAX;
            s[mf][2] = ((mi & (bits >> 2)) & 1u) ? s[mf][2] + bv.z : NEG_MAX;
            s[mf][3] = ((mi & (bits >> 3)) & 1u) ? s[mf][3] + bv.w : NEG_MAX;
        }

        // online softmax
        float tm = s[0][0];
#pragma unroll
        for (int mf = 0; mf < 4; mf++)
#pragma unroll
            for (int r = 0; r < 4; r++) tm = fmaxf(tm, s[mf][r]);
        tm = fmaxf(tm, __shfl_xor(tm, 16));
        tm = fmaxf(tm, __shfl_xor(tm, 32));
        float mnew = fmaxf(m_run, tm);
        float corr = __expf(m_run - mnew);
        m_run = mnew;
#pragma unroll
        for (int md = 0; md < 2; md++)
#pragma unroll
            for (int r = 0; r < 4; r++) acc_o[md][r] *= corr;
        float ls = 0.f;
#pragma unroll
        for (int mf = 0; mf < 4; mf++)
#pragma unroll
            for (int r = 0; r < 4; r++) {
                float wv = __expf(s[mf][r] - mnew);
                s[mf][r] = wv;
                ls += wv;
            }
        ls += __shfl_xor(ls, 16);
        ls += __shfl_xor(ls, 32);
        l_run = l_run * corr + ls;

        // PV: pack all 64 j-cols to LDS, single wait, 4 MFMAs
#pragma unroll
        for (int mf = 0; mf < 4; mf++) {
            uint2 hv;
            hv.x = (uint_t)f2bf(s[mf][0]) | ((uint_t)f2bf(s[mf][1]) << 16);
            hv.y = (uint_t)f2bf(s[mf][2]) | ((uint_t)f2bf(s[mf][3]) << 16);
            *(uint2*)(pbh + lr * 88 + mf * 16 + lg * 4) = hv;
        }
        asm volatile("s_waitcnt lgkmcnt(0)" ::: "memory");
        __builtin_amdgcn_sched_barrier(0);
        short8v ph0 = *(const short8v*)(pbh + lr * 88 + lg * 8);
        short8v ph1 = *(const short8v*)(pbh + lr * 88 + 32 + lg * 8);
        __builtin_amdgcn_s_setprio(1);
        acc_o[0] = __builtin_amdgcn_mfma_f32_16x16x32_bf16(
            vf[0], ph0, acc_o[0], 0, 0, 0);
        acc_o[1] = __builtin_amdgcn_mfma_f32_16x16x32_bf16(
            vf[1], ph0, acc_o[1], 0, 0, 0);
        acc_o[0] = __builtin_amdgcn_mfma_f32_16x16x32_bf16(
            vf[2], ph1, acc_o[0], 0, 0, 0);
        acc_o[1] = __builtin_amdgcn_mfma_f32_16x16x32_bf16(
            vf[3], ph1, acc_o[1], 0, 0, 0);
        __builtin_amdgcn_s_setprio(0);
    }

    // epilogue: O = acc/l * gate (preloaded), bf16 hi only
    float invl = 1.0f / l_run;
#pragma unroll
    for (int md = 0; md < 2; md++) {
        uint2 gv = (md == 0) ? gva : gvb;
        float g0 = bf2f((ushort_t)(gv.x & 0xffff));
        float g1 = bf2f((ushort_t)(gv.x >> 16));
        float g2 = bf2f((ushort_t)(gv.y & 0xffff));
        float g3 = bf2f((ushort_t)(gv.y >> 16));
        int i = i0 + lr;
        int d0 = md * 16 + lg * 4;
        size_t base = ((size_t)(b * 256 + i)) * 256 + h * 32 + d0;
        ushort4 hh;
        hh.x = f2bf(acc_o[md][0] * invl * g0);
        hh.y = f2bf(acc_o[md][1] * invl * g1);
        hh.z = f2bf(acc_o[md][2] * invl * g2);
        hh.w = f2bf(acc_o[md][3] * invl * g3);
        *(ushort4*)(atthi + base) = hh;
    }
}

// ---------------------------------------------------------------------------
extern "C" void kernel_launch(void* const* d_in, const int* in_sizes, int n_in,
                              void* d_out, int out_size, void* d_ws, size_t ws_size,
                              hipStream_t stream) {
    const float* x    = (const float*)d_in[0];
    const unsigned char* mraw = (const unsigned char*)d_in[1];
    const float* bias = (const float*)d_in[2];
    const float* Wq   = (const float*)d_in[3];
    const float* Wkv  = (const float*)d_in[4];
    const float* Wg   = (const float*)d_in[5];
    const float* bg   = (const float*)d_in[6];
    const float* Wo   = (const float*)d_in[7];
    const float* bo   = (const float*)d_in[8];

    float* ws = (float*)d_ws;
    ushort_t* kh     = (ushort_t*)(ws + OFF_KH);
    ushort_t* vP     = (ushort_t*)(ws + OFF_VP);
    ushort_t* gatesP = (ushort_t*)(ws + OFF_GATES);
    ushort_t* xhi    = (ushort_t*)(ws + OFF_XHI);
    ushort_t* atthi  = (ushort_t*)(ws + OFF_ATTHI);  // aliases xhi (dead)
    ushort_t* bthi   = (ushort_t*)(ws + OFF_BTHI);
    ushort_t* btlo   = (ushort_t*)(ws + OFF_BTLO);
    ushort_t* qPh    = (ushort_t*)(ws + OFF_QTH);
    float*    biasP  = ws + OFF_BIASP;
    uint_t*   maskb  = (uint_t*)(ws + OFF_MASK);

    hipLaunchKernelGGL(prep_kernel, dim3(1793), dim3(256), 0, stream,
                       x, mraw, bias, Wkv, Wg, Wo, Wq,
                       xhi, maskb, bthi, btlo, biasP, qPh);
    // proj: M=16384, N=768, 128x128 tiles, 1-term, dbuf, XCD swizzle
    hipLaunchKernelGGL((mfma_gemm<0, 4, 4, 1>), dim3(768), dim3(256), 0, stream,
                       xhi, xhi, bthi, btlo, bg, (float*)nullptr,
                       kh, vP, gatesP, 6);
    hipLaunchKernelGGL(attn_mfma_kernel, dim3(2048), dim3(256), 0, stream,
                       qPh, kh, vP, gatesP, biasP, maskb, atthi);
    // out = att @ Wo + bo : TERMS=4 (ah*bh + ah*bl), 64x64 tiles, 1024 blocks
    hipLaunchKernelGGL((mfma_gemm<1, 2, 2, 4>), dim3(1024), dim3(256), 0, stream,
                       atthi, atthi, bthi + 768 * 256, btlo + 768 * 256, bo,
                       (float*)d_out, nullptr, nullptr, nullptr, 4);
}